// Round 3
// baseline (105.251 us; speedup 1.0000x reference)
//
#include <hip/hip_runtime.h>
#include <math.h>

#define NC 17
#define PLANE 640000            // 200*200*16
#define Q (PLANE / 4)           // 160000 float4 per channel-plane
#define BPB 625                 // blocks per batch = Q/256
#define NBLK (2 * BPB)          // 1250 blocks total
#define BETA_C 0.95f
#define ALPHA_C 5.0f
#define WPC_C 3.0f
#define IGNORE_C 255

__device__ __forceinline__ float bce_ones(float x) {
    // F.binary_cross_entropy(x, ones) = min(-log(max(x,1e-38)), 100)
    return fminf(-logf(fmaxf(x, 1e-38f)), 100.0f);
}

// ---------------------------------------------------------------------------
// Fused: softmax + per-class sums + (last block) scalar epilogue.
// acc layout (3*NC floats): [0..16]=nominator, [17..33]=sum_p, [34..50]=sum_comp
// done: 1 uint counter after acc.
// ---------------------------------------------------------------------------
__global__ __launch_bounds__(256, 4) void al_fused(const float* __restrict__ pred,
                                                   const int* __restrict__ tgt,
                                                   const float* __restrict__ f1_list,
                                                   float* __restrict__ out,
                                                   float* __restrict__ acc,
                                                   unsigned* __restrict__ done) {
    const int bb = blockIdx.x;
    const int b  = (bb >= BPB) ? 1 : 0;                    // block-uniform -> SGPR
    const int n4 = (bb - b * BPB) * 256 + (int)threadIdx.x; // 0..Q-1
    const float4* p0 = reinterpret_cast<const float4*>(pred)
                       + (size_t)(b * NC) * Q + n4;
    const int4 t4 = reinterpret_cast<const int4*>(tgt)[b * Q + n4];

    // Issue ALL 17 channel loads before any consumer (272 B/lane in flight).
    float4 x[NC];
#pragma unroll
    for (int c = 0; c < NC; ++c) x[c] = p0[(size_t)c * Q];
    __builtin_amdgcn_sched_barrier(0);

    // per-sub-voxel max
    float4 mx = x[0];
#pragma unroll
    for (int c = 1; c < NC; ++c) {
        mx.x = fmaxf(mx.x, x[c].x);
        mx.y = fmaxf(mx.y, x[c].y);
        mx.z = fmaxf(mx.z, x[c].z);
        mx.w = fmaxf(mx.w, x[c].w);
    }

    // exp + denom
    float4 s = make_float4(0.f, 0.f, 0.f, 0.f);
#pragma unroll
    for (int c = 0; c < NC; ++c) {
        x[c].x = __expf(x[c].x - mx.x); s.x += x[c].x;
        x[c].y = __expf(x[c].y - mx.y); s.y += x[c].y;
        x[c].z = __expf(x[c].z - mx.z); s.z += x[c].z;
        x[c].w = __expf(x[c].w - mx.w); s.w += x[c].w;
    }

    // fold ignore-mask into the reciprocal: p = x * (w / s)
    const float i0 = ((t4.x != IGNORE_C) ? 1.0f : 0.0f) / s.x;
    const float i1 = ((t4.y != IGNORE_C) ? 1.0f : 0.0f) / s.y;
    const float i2 = ((t4.z != IGNORE_C) ? 1.0f : 0.0f) / s.z;
    const float i3 = ((t4.w != IGNORE_C) ? 1.0f : 0.0f) / s.w;

    __shared__ float lds[3 * NC];
    if (threadIdx.x < 3 * NC) lds[threadIdx.x] = 0.f;
    __syncthreads();

    // per-channel: partials -> wave butterfly -> LDS atomic (short live ranges)
#pragma unroll
    for (int c = 0; c < NC; ++c) {
        const float px = x[c].x * i0;
        const float py = x[c].y * i1;
        const float pz = x[c].z * i2;
        const float pw = x[c].w * i3;
        float sump = (px + py) + (pz + pw);
        float nom  = ((t4.x == c) ? px : 0.f) + ((t4.y == c) ? py : 0.f)
                   + ((t4.z == c) ? pz : 0.f) + ((t4.w == c) ? pw : 0.f);
        float cnt  = ((t4.x == c) ? 1.f : 0.f) + ((t4.y == c) ? 1.f : 0.f)
                   + ((t4.z == c) ? 1.f : 0.f) + ((t4.w == c) ? 1.f : 0.f);
#pragma unroll
        for (int off = 32; off > 0; off >>= 1) {
            nom  += __shfl_down(nom,  (unsigned)off, 64);
            sump += __shfl_down(sump, (unsigned)off, 64);
            cnt  += __shfl_down(cnt,  (unsigned)off, 64);
        }
        if ((threadIdx.x & 63) == 0) {
            atomicAdd(&lds[c],          nom);
            atomicAdd(&lds[NC + c],     sump);
            atomicAdd(&lds[2 * NC + c], cnt);
        }
    }
    __syncthreads();
    if (threadIdx.x < 3 * NC) atomicAdd(&acc[threadIdx.x], lds[threadIdx.x]);

    // -------------------- last-block-done epilogue --------------------
    __shared__ int is_last;
    __threadfence();
    if (threadIdx.x == 0) {
        const unsigned old = atomicAdd(done, 1u);
        is_last = (old == (unsigned)(gridDim.x - 1)) ? 1 : 0;
    }
    __syncthreads();
    if (!is_last) return;
    __threadfence();
    if (threadIdx.x != 0) return;

    float nomA[NC], sumpA[NC], cntA[NC];
    float n_mask = 0.f;
    for (int c = 0; c < NC; ++c) {
        nomA[c]  = __hip_atomic_load(&acc[c],          __ATOMIC_RELAXED, __HIP_MEMORY_SCOPE_AGENT);
        sumpA[c] = __hip_atomic_load(&acc[NC + c],     __ATOMIC_RELAXED, __HIP_MEMORY_SCOPE_AGENT);
        cntA[c]  = __hip_atomic_load(&acc[2 * NC + c], __ATOMIC_RELAXED, __HIP_MEMORY_SCOPE_AGENT);
        n_mask += cntA[c];
    }

    float loss_list[NC], newf1[NC];
    float count = 0.f;
    for (int c = 0; c < NC; ++c) {
        const bool has = cntA[c] > 0.f;
        const float prec = (sumpA[c] > 0.f) ? nomA[c] / sumpA[c] : 0.f;
        const float rec  = has ? nomA[c] / cntA[c] : 0.f;
        const float negc = n_mask - cntA[c];
        const float spec_num = (n_mask - sumpA[c]) - (cntA[c] - nomA[c]);
        const float spec = (negc > 0.f) ? spec_num / negc : 0.f;

        float ll = 0.f;
        if (has) {
            ll  = (sumpA[c] > 0.f) ? bce_ones(prec) : 0.f;
            ll += bce_ones(rec);
            ll += (negc > 0.f) ? bce_ones(spec) : 0.f;
        }
        loss_list[c] = ll;

        const float den = prec + rec;
        const float f1  = (den > 0.f) ? 2.f * prec * rec / den : 0.f;
        const float cur = has ? f1 : 0.f;
        newf1[c] = BETA_C * f1_list[c] + (1.f - BETA_C) * cur;
        count += has ? 1.f : 0.f;
    }

    const float wp = WPC_C * count;

    float mxl = -INFINITY;
    for (int c = 0; c < NC; ++c) {
        const float lg = (loss_list[c] != 0.f) ? ALPHA_C * (1.f - newf1[c]) : -INFINITY;
        mxl = fmaxf(mxl, lg);
    }
    float e[NC];
    float se = 0.f;
    for (int c = 0; c < NC; ++c) {
        const float lg = (loss_list[c] != 0.f) ? ALPHA_C * (1.f - newf1[c]) : -INFINITY;
        e[c] = expf(lg - mxl);     // exp(-inf) = 0 for unselected classes
        se += e[c];
    }

    float total = 0.f;
    for (int c = 0; c < NC; ++c) {
        const float sm = e[c] / se;
        total += loss_list[c] * (1.f + wp * sm);
    }
    out[0] = total / (count * (1.f + WPC_C));
}

// ---------------------------------------------------------------------------
extern "C" void kernel_launch(void* const* d_in, const int* in_sizes, int n_in,
                              void* d_out, int out_size, void* d_ws, size_t ws_size,
                              hipStream_t stream) {
    const float* pred    = (const float*)d_in[0];
    const int*   tgt     = (const int*)d_in[1];
    const float* f1_list = (const float*)d_in[2];
    float* out = (float*)d_out;
    float* acc = (float*)d_ws;                 // 51 floats
    unsigned* done = (unsigned*)(acc + 3 * NC); // 1 uint

    hipMemsetAsync(d_ws, 0, (3 * NC + 1) * sizeof(float), stream);
    al_fused<<<dim3(NBLK), dim3(256), 0, stream>>>(pred, tgt, f1_list, out, acc, done);
}